// Round 8
// baseline (15029.010 us; speedup 1.0000x reference)
//
#include <hip/hip_runtime.h>
#include <hip/hip_bf16.h>

#define DEV __device__ __forceinline__

constexpr int Mn  = 30000;   // nodes (B=1)
constexpr int Tt  = 12;
constexpr int CIN = 16;
constexpr int Hh  = 64;
constexpr int Gg  = 192;     // 3H
constexpr int C2  = 128;     // 2H
constexpr int Ee  = 960000;  // edges per timestep (bidirectional)
constexpr int HC  = 128;
constexpr int Oo  = 12;
constexpr int KW  = 128;
constexpr int HP  = 72;      // padded h row stride (floats)
constexpr int NB  = 235;     // 128-row buckets per t (235*128 >= 30000)
constexpr int EPB = 8192;    // edges per block for bcnt/part2
constexpr int BPT = 118;     // ceil(Ee/EPB)

DEV float bf2f(__hip_bfloat16 v){ return __bfloat162float(v); }
DEV __hip_bfloat16 f2bf(float v){ return __float2bfloat16(v); }
DEV float sigm(float x){ return __builtin_amdgcn_rcpf(1.f + __expf(-x)); }
DEV float tanh_f(float x){ return 1.f - 2.f*__builtin_amdgcn_rcpf(__expf(2.f*x) + 1.f); }

typedef short bfrag8 __attribute__((ext_vector_type(8)));
typedef float ffrag4 __attribute__((ext_vector_type(4)));

// ---------------------------------------------------------------- init
__global__ void k_init(int* bcnt, int* bfill){
  int i = blockIdx.x*256 + threadIdx.x;
  if (i < Tt*NB){ bcnt[i] = 0; bfill[i] = 0; }
}

// ---------------------------------------------------------------- stage 1: block-aggregated bucket histogram
__global__ __launch_bounds__(256) void k_bcnt(const int* __restrict__ ei, int* __restrict__ bcnt){
  __shared__ int h[NB];
  const int b = blockIdx.x;                 // 1416 = 8*177
  const int w = (b & 7)*177 + (b >> 3);
  const int t = w / BPT, ch = w - t*BPT;
  const int e0 = ch*EPB;
  const int tid = threadIdx.x;
  for (int i = tid; i < NB; i += 256) h[i] = 0;
  __syncthreads();
  #pragma unroll
  for (int i = 0; i < 32; ++i){
    int e = e0 + i*256 + tid;
    if (e < Ee){
      int r = ei[(size_t)(t*2)*Ee + e];
      atomicAdd(&h[r >> 7], 1);
    }
  }
  __syncthreads();
  for (int i = tid; i < NB; i += 256){
    int c = h[i];
    if (c > 0) atomicAdd(&bcnt[t*NB + i], c);
  }
}

// ---------------------------------------------------------------- stage 2: per-t exclusive scan of bucket counts
__global__ __launch_bounds__(256) void k_bscan(const int* __restrict__ bcnt, int* __restrict__ rpb){
  int t = blockIdx.x, tid = threadIdx.x;
  __shared__ int ps[256];
  int v = (tid < NB) ? bcnt[t*NB + tid] : 0;
  ps[tid] = v;
  __syncthreads();
  for (int o = 1; o < 256; o <<= 1){
    int x = (tid >= o) ? ps[tid-o] : 0;
    __syncthreads();
    ps[tid] += x;
    __syncthreads();
  }
  if (tid < NB) rpb[t*(NB+1) + tid] = ps[tid] - v;
  if (tid == 255) rpb[t*(NB+1) + NB] = ps[NB-1];
}

// ---------------------------------------------------------------- stage 3: partition edges into buckets (block-aggregated reservations)
__global__ __launch_bounds__(256) void k_part2(const int* __restrict__ ei, const int* __restrict__ rpb,
    int* __restrict__ bfill, unsigned* __restrict__ pair){
  __shared__ int hcnt[NB];
  __shared__ int hbase[NB];
  const int b = blockIdx.x;                 // 1416 = 8*177
  const int w = (b & 7)*177 + (b >> 3);
  const int t = w / BPT, ch = w - t*BPT;
  const int e0 = ch*EPB;
  const int tid = threadIdx.x;
  for (int i = tid; i < NB; i += 256) hcnt[i] = 0;
  __syncthreads();
  unsigned key[32];
  #pragma unroll
  for (int i = 0; i < 32; ++i){
    int e = e0 + i*256 + tid;
    unsigned k = 0xFFFFFFFFu;
    if (e < Ee){
      int r = ei[(size_t)(t*2)*Ee + e];
      int c = ei[(size_t)(t*2+1)*Ee + e];
      k = ((unsigned)r << 16) | (unsigned)c;
      atomicAdd(&hcnt[r >> 7], 1);
    }
    key[i] = k;
  }
  __syncthreads();
  for (int i = tid; i < NB; i += 256){
    int cnt = hcnt[i];
    int base = (cnt > 0) ? atomicAdd(&bfill[t*NB + i], cnt) : 0;
    hbase[i] = rpb[t*(NB+1) + i] + base;
  }
  __syncthreads();
  for (int i = tid; i < NB; i += 256) hcnt[i] = 0;
  __syncthreads();
  #pragma unroll
  for (int i = 0; i < 32; ++i){
    unsigned k = key[i];
    if (k != 0xFFFFFFFFu){
      int r = (int)(k >> 16);
      int bk = r >> 7;
      int pos = atomicAdd(&hcnt[bk], 1);
      pair[(size_t)t*Ee + hbase[bk] + pos] = ((unsigned)(r & 127) << 16) | (k & 0xFFFFu);
    }
  }
}

// ---------------------------------------------------------------- stage 4: per-bucket LDS counting sort -> col16, rp, deg
__global__ __launch_bounds__(256) void k_csr2(const int* __restrict__ rpb, const unsigned* __restrict__ pair,
    unsigned short* __restrict__ col16, int* __restrict__ rp, int* __restrict__ deg){
  __shared__ unsigned short cols_s[9216];
  __shared__ int lcnt[128], lfill[128];
  __shared__ int ps[256];
  const int blk = blockIdx.x;               // Tt*NB
  const int t = blk / NB, bk = blk - t*NB;
  const int r0 = bk << 7;
  const int nr = (r0 + 128 <= Mn) ? 128 : (Mn - r0);
  const int base = rpb[t*(NB+1) + bk];
  const int cnt  = rpb[t*(NB+1) + bk + 1] - base;
  const int tid = threadIdx.x;
  if (tid < 128) lcnt[tid] = 0;
  __syncthreads();
  for (int i = tid; i < cnt; i += 256){
    unsigned v = pair[(size_t)t*Ee + base + i];
    atomicAdd(&lcnt[v >> 16], 1);
  }
  __syncthreads();
  int v2 = (tid < 128) ? lcnt[tid] : 0;
  ps[tid] = v2;
  __syncthreads();
  for (int o = 1; o < 128; o <<= 1){
    int x = (tid >= o) ? ps[tid-o] : 0;
    __syncthreads();
    ps[tid] += x;
    __syncthreads();
  }
  if (tid < 128){
    int excl = ps[tid] - v2;
    lfill[tid] = excl;
    if (tid < nr){
      rp[t*(Mn+1) + r0 + tid] = base + excl;
      deg[t*Mn + r0 + tid] = v2;
    }
  }
  if (bk == NB-1 && tid == 0) rp[t*(Mn+1) + Mn] = base + cnt;
  __syncthreads();
  for (int i = tid; i < cnt; i += 256){
    unsigned v = pair[(size_t)t*Ee + base + i];
    int pos = atomicAdd(&lfill[v >> 16], 1);
    cols_s[pos] = (unsigned short)(v & 0xFFFFu);
  }
  __syncthreads();
  for (int i = tid; i < cnt; i += 256)
    col16[(size_t)t*Ee + base + i] = cols_s[i];
}

// ---------------------------------------------------------------- dinv
__global__ void k_dinv(const int* __restrict__ deg, float* __restrict__ dinv){
  int i = blockIdx.x*256 + threadIdx.x;
  if (i < Tt*Mn){ int d = deg[i]; dinv[i] = (d > 0) ? rsqrtf((float)d) : 0.f; }
}

// ---------------------------------------------------------------- GRU layer 0 (both dirs), writes y0 (T,M,128) bf16
__global__ __launch_bounds__(256) void k_gru0(
    const float* __restrict__ nf, const float* __restrict__ Wih, const float* __restrict__ Whh,
    const float* __restrict__ bih, const float* __restrict__ bhh, __hip_bfloat16* __restrict__ y0)
{
  __shared__ float xs[Tt][CIN][32];
  __shared__ __hip_bfloat16 wi[CIN][Gg];
  __shared__ __hip_bfloat16 wh[Hh][Gg];
  __shared__ float hb[32][HP];
  __shared__ float bi[Gg], bh[Gg];
  const int tid = threadIdx.x;
  const int m0  = blockIdx.x*32;
  for (int idx = tid; idx < Tt*32*CIN; idx += 256){
    int t = idx / (32*CIN); int rr = (idx / CIN) & 31; int k = idx & (CIN-1);
    int m = m0 + rr;
    xs[t][k][rr] = (m < Mn) ? nf[((size_t)t*Mn + m)*CIN + k] : 0.f;
  }
  const int jg = tid & 31, rg = tid >> 5;
  const int j0 = jg*2, rg4 = rg*4;
  for (int d = 0; d < 2; ++d){
    __syncthreads();
    for (int idx = tid; idx < Gg*CIN; idx += 256){
      int g = idx / CIN, k = idx & (CIN-1);
      wi[k][g] = f2bf(Wih[((size_t)d*Gg + g)*CIN + k]);
    }
    for (int idx = tid; idx < Gg*Hh; idx += 256){
      int g = idx >> 6, k = idx & 63;
      wh[k][g] = f2bf(Whh[((size_t)d*Gg + g)*Hh + k]);
    }
    if (tid < Gg){ bi[tid] = bih[d*Gg + tid]; bh[tid] = bhh[d*Gg + tid]; }
    for (int idx = tid; idx < 32*HP; idx += 256) ((float*)hb)[idx] = 0.f;
    __syncthreads();
    for (int step = 0; step < Tt; ++step){
      int t = d ? (Tt-1-step) : step;
      float ar[4][2], az[4][2], ai[4][2], ah[4][2];
      #pragma unroll
      for (int i = 0; i < 4; ++i){
        #pragma unroll
        for (int jj = 0; jj < 2; ++jj){
          int j = j0 + jj;
          ar[i][jj] = bi[j] + bh[j];
          az[i][jj] = bi[Hh+j] + bh[Hh+j];
          ai[i][jj] = bi[2*Hh+j];
          ah[i][jj] = bh[2*Hh+j];
        }
      }
      #pragma unroll
      for (int k = 0; k < CIN; ++k){
        float4 xv4 = *(const float4*)&xs[t][k][rg4];
        float xv[4] = {xv4.x, xv4.y, xv4.z, xv4.w};
        __hip_bfloat162 pr = *(const __hip_bfloat162*)&wi[k][j0];
        __hip_bfloat162 pz = *(const __hip_bfloat162*)&wi[k][Hh+j0];
        __hip_bfloat162 pn = *(const __hip_bfloat162*)&wi[k][2*Hh+j0];
        float wr[2] = {bf2f(pr.x), bf2f(pr.y)};
        float wz[2] = {bf2f(pz.x), bf2f(pz.y)};
        float wn[2] = {bf2f(pn.x), bf2f(pn.y)};
        #pragma unroll
        for (int i = 0; i < 4; ++i){
          #pragma unroll
          for (int jj = 0; jj < 2; ++jj){
            ar[i][jj] += xv[i]*wr[jj];
            az[i][jj] += xv[i]*wz[jj];
            ai[i][jj] += xv[i]*wn[jj];
          }
        }
      }
      #pragma unroll 4
      for (int k4 = 0; k4 < 16; ++k4){
        float4 h0 = *(const float4*)&hb[rg4+0][k4*4];
        float4 h1 = *(const float4*)&hb[rg4+1][k4*4];
        float4 h2 = *(const float4*)&hb[rg4+2][k4*4];
        float4 h3 = *(const float4*)&hb[rg4+3][k4*4];
        #pragma unroll
        for (int kk = 0; kk < 4; ++kk){
          int k = k4*4 + kk;
          float hv[4] = { ((const float*)&h0)[kk], ((const float*)&h1)[kk],
                          ((const float*)&h2)[kk], ((const float*)&h3)[kk] };
          __hip_bfloat162 pr = *(const __hip_bfloat162*)&wh[k][j0];
          __hip_bfloat162 pz = *(const __hip_bfloat162*)&wh[k][Hh+j0];
          __hip_bfloat162 pn = *(const __hip_bfloat162*)&wh[k][2*Hh+j0];
          float wr[2] = {bf2f(pr.x), bf2f(pr.y)};
          float wz[2] = {bf2f(pz.x), bf2f(pz.y)};
          float wn[2] = {bf2f(pn.x), bf2f(pn.y)};
          #pragma unroll
          for (int i = 0; i < 4; ++i){
            #pragma unroll
            for (int jj = 0; jj < 2; ++jj){
              ar[i][jj] += hv[i]*wr[jj];
              az[i][jj] += hv[i]*wz[jj];
              ah[i][jj] += hv[i]*wn[jj];
            }
          }
        }
      }
      __syncthreads();
      #pragma unroll
      for (int i = 0; i < 4; ++i){
        int r = rg4 + i; int m = m0 + r;
        float hn2[2];
        #pragma unroll
        for (int jj = 0; jj < 2; ++jj){
          float rr = sigm(ar[i][jj]);
          float zz = sigm(az[i][jj]);
          float nn = tanh_f(ai[i][jj] + rr*ah[i][jj]);
          float hv = hb[r][j0+jj];
          hn2[jj] = (1.f-zz)*nn + zz*hv;
          hb[r][j0+jj] = hn2[jj];
        }
        if (m < Mn){
          __hip_bfloat162 pk; pk.x = f2bf(hn2[0]); pk.y = f2bf(hn2[1]);
          *(__hip_bfloat162*)&y0[((size_t)t*Mn + m)*C2 + d*Hh + j0] = pk;
        }
      }
      __syncthreads();
    }
  }
}

// ---------------------------------------------------------------- convert layer-1 reverse weights to bf16
__global__ void k_wcvt(const float* __restrict__ W, __hip_bfloat16* __restrict__ Wbf){
  int i = blockIdx.x*256 + threadIdx.x;
  if (i < Gg*C2) Wbf[i] = f2bf(W[i]);
}

// ---------------------------------------------------------------- layer-1 input projection via MFMA
__global__ __launch_bounds__(256) void k_gi1m(const __hip_bfloat16* __restrict__ y0,
    const __hip_bfloat16* __restrict__ Wbf, const float* __restrict__ bih, __hip_bfloat16* __restrict__ gi)
{
  const int wid  = (blockIdx.x*256 + threadIdx.x) >> 6;
  const int lane = threadIdx.x & 63;
  const int SEGS = (Mn + 31)/32;
  if (wid >= Tt*SEGS) return;
  const int t = wid / SEGS, seg = wid - t*SEGS;
  const int m0 = seg*32;
  const int lr = lane & 15, lq = lane >> 4;
  const __hip_bfloat16* yb = y0 + (size_t)t*Mn*C2;

  ffrag4 acc[2][12];
  #pragma unroll
  for (int i = 0; i < 2; ++i){
    #pragma unroll
    for (int n = 0; n < 12; ++n) acc[i][n] = (ffrag4){0.f,0.f,0.f,0.f};
  }
  #pragma unroll
  for (int ks = 0; ks < 4; ++ks){
    const int ko = ks*32 + lq*8;
    bfrag8 a0 = *(const bfrag8*)(yb + (size_t)(m0 + lr     )*C2 + ko);
    bfrag8 a1 = *(const bfrag8*)(yb + (size_t)(m0 + 16 + lr)*C2 + ko);
    #pragma unroll
    for (int nt = 0; nt < 12; ++nt){
      bfrag8 b = *(const bfrag8*)(Wbf + (size_t)(nt*16 + lr)*C2 + ko);
      acc[0][nt] = __builtin_amdgcn_mfma_f32_16x16x32_bf16(a0, b, acc[0][nt], 0, 0, 0);
      acc[1][nt] = __builtin_amdgcn_mfma_f32_16x16x32_bf16(a1, b, acc[1][nt], 0, 0, 0);
    }
  }
  #pragma unroll
  for (int nt = 0; nt < 12; ++nt){
    int g = nt*16 + lr;
    float bb = bih[g];
    #pragma unroll
    for (int r = 0; r < 4; ++r){
      int mm0 = m0 + lq*4 + r;
      int mm1 = mm0 + 16;
      if (mm0 < Mn) gi[((size_t)t*Mn + mm0)*Gg + g] = f2bf(acc[0][nt][r] + bb);
      if (mm1 < Mn) gi[((size_t)t*Mn + mm1)*Gg + g] = f2bf(acc[1][nt][r] + bb);
    }
  }
}

// ---------------------------------------------------------------- GRU layer 1 (reverse only) + fused LayerNorm
__global__ __launch_bounds__(256) void k_gru1r(const __hip_bfloat16* __restrict__ gi,
    const float* __restrict__ Whh, const float* __restrict__ bhh,
    const float* __restrict__ lns, const float* __restrict__ lnb,
    __hip_bfloat16* __restrict__ xbt)
{
  __shared__ __hip_bfloat16 wh[Hh][Gg];
  __shared__ float hb[32][HP];
  __shared__ float bh[Gg];
  __shared__ float sc[Hh], bs[Hh];
  const int tid = threadIdx.x;
  const int m0  = blockIdx.x*32;
  for (int idx = tid; idx < Gg*Hh; idx += 256){
    int g = idx >> 6, k = idx & 63;
    wh[k][g] = f2bf(Whh[(size_t)g*Hh + k]);
  }
  if (tid < Gg) bh[tid] = bhh[tid];
  if (tid < Hh){ sc[tid] = lns[tid]; bs[tid] = lnb[tid]; }
  for (int idx = tid; idx < 32*HP; idx += 256) ((float*)hb)[idx] = 0.f;
  __syncthreads();
  const int jg = tid & 31, rg = tid >> 5;
  const int j0 = jg*2, rg4 = rg*4;
  for (int step = 0; step < Tt; ++step){
    int t = Tt-1-step;
    float ar[4][2], az[4][2], ai[4][2], ah[4][2];
    #pragma unroll
    for (int i = 0; i < 4; ++i){
      int m = m0 + rg4 + i;
      int mc = (m < Mn) ? m : 0;
      const __hip_bfloat16* gp = gi + ((size_t)t*Mn + mc)*Gg;
      __hip_bfloat162 pr = *(const __hip_bfloat162*)&gp[j0];
      __hip_bfloat162 pz = *(const __hip_bfloat162*)&gp[Hh+j0];
      __hip_bfloat162 pn = *(const __hip_bfloat162*)&gp[2*Hh+j0];
      #pragma unroll
      for (int jj = 0; jj < 2; ++jj){
        int j = j0 + jj;
        float gr = jj ? bf2f(pr.y) : bf2f(pr.x);
        float gz = jj ? bf2f(pz.y) : bf2f(pz.x);
        float gn = jj ? bf2f(pn.y) : bf2f(pn.x);
        ar[i][jj] = gr + bh[j];
        az[i][jj] = gz + bh[Hh+j];
        ai[i][jj] = gn;
        ah[i][jj] = bh[2*Hh+j];
      }
    }
    #pragma unroll 4
    for (int k4 = 0; k4 < 16; ++k4){
      float4 h0 = *(const float4*)&hb[rg4+0][k4*4];
      float4 h1 = *(const float4*)&hb[rg4+1][k4*4];
      float4 h2 = *(const float4*)&hb[rg4+2][k4*4];
      float4 h3 = *(const float4*)&hb[rg4+3][k4*4];
      #pragma unroll
      for (int kk = 0; kk < 4; ++kk){
        int k = k4*4 + kk;
        float hv[4] = { ((const float*)&h0)[kk], ((const float*)&h1)[kk],
                        ((const float*)&h2)[kk], ((const float*)&h3)[kk] };
        __hip_bfloat162 pr = *(const __hip_bfloat162*)&wh[k][j0];
        __hip_bfloat162 pz = *(const __hip_bfloat162*)&wh[k][Hh+j0];
        __hip_bfloat162 pn = *(const __hip_bfloat162*)&wh[k][2*Hh+j0];
        float wr[2] = {bf2f(pr.x), bf2f(pr.y)};
        float wz[2] = {bf2f(pz.x), bf2f(pz.y)};
        float wn[2] = {bf2f(pn.x), bf2f(pn.y)};
        #pragma unroll
        for (int i = 0; i < 4; ++i){
          #pragma unroll
          for (int jj = 0; jj < 2; ++jj){
            ar[i][jj] += hv[i]*wr[jj];
            az[i][jj] += hv[i]*wz[jj];
            ah[i][jj] += hv[i]*wn[jj];
          }
        }
      }
    }
    __syncthreads();
    #pragma unroll
    for (int i = 0; i < 4; ++i){
      int r = rg4 + i;
      #pragma unroll
      for (int jj = 0; jj < 2; ++jj){
        float rr = sigm(ar[i][jj]);
        float zz = sigm(az[i][jj]);
        float nn = tanh_f(ai[i][jj] + rr*ah[i][jj]);
        float hv = hb[r][j0+jj];
        hb[r][j0+jj] = (1.f-zz)*nn + zz*hv;
      }
    }
    __syncthreads();
    {
      int r = tid >> 3, l = tid & 7;
      float vals[8];
      float s1 = 0.f, s2 = 0.f;
      #pragma unroll
      for (int q = 0; q < 8; ++q){ float v = hb[r][l + 8*q]; vals[q] = v; s1 += v; s2 += v*v; }
      #pragma unroll
      for (int off = 1; off <= 4; off <<= 1){ s1 += __shfl_xor(s1, off); s2 += __shfl_xor(s2, off); }
      float mu  = s1 * (1.f/64.f);
      float var = s2 * (1.f/64.f) - mu*mu;
      float rs  = rsqrtf(var + 1e-5f);
      int m = m0 + r;
      if (m < Mn){
        __hip_bfloat16* op = xbt + ((size_t)t*Mn + m)*Hh;
        #pragma unroll
        for (int q = 0; q < 8; ++q){ int j = l + 8*q; op[j] = f2bf((vals[q]-mu)*rs*sc[j] + bs[j]); }
      }
    }
    __syncthreads();
  }
}

// ---------------------------------------------------------------- FULL power iteration for one t in ONE block: u lives in LDS.
// Same deferred-normalization recurrence as validated R2-R6; no global u, no cross-block sync.
__global__ __launch_bounds__(1024) void k_pitc2(const int* __restrict__ rp,
    const unsigned short* __restrict__ col, float* __restrict__ lamc)
{
  __shared__ float u_s[Mn];                 // 117.2 KB, fits 160 KB LDS
  __shared__ float redw[16];
  __shared__ float nprev;
  const int t = blockIdx.x;                 // 12 blocks, one per timestep
  const int tid = threadIdx.x;
  const int* rpt = rp + t*(Mn+1);
  const unsigned short* cp = col + (size_t)t*Ee;
  for (int i = tid; i < Mn; i += 1024) u_s[i] = 0.005773502691896258f; // 1/sqrt(30000)
  if (tid == 0) nprev = 1.0f;
  __syncthreads();
  float wreg[30];
  for (int r = 1; r <= 76; ++r){
    const int fin = (r == 76);
    // phase 1: gather w = deg*u - sum_nb u into registers (deg = rp[m+1]-rp[m])
    #pragma unroll
    for (int it = 0; it < 30; ++it){
      int m = tid + it*1024;
      float wv = 0.f;
      if (m < Mn){
        int bgn = rpt[m], end = rpt[m+1];
        float s = 0.f;
        int i = bgn;
        for (; i < end && (i & 3); ++i) s += u_s[cp[i]];
        for (; i + 4 <= end; i += 4){
          ushort4 c4 = *(const ushort4*)(cp + i);
          s += (u_s[c4.x] + u_s[c4.y]) + (u_s[c4.z] + u_s[c4.w]);
        }
        for (; i < end; ++i) s += u_s[cp[i]];
        wv = (float)(end - bgn)*u_s[m] - s;
      }
      wreg[it] = wv;
    }
    __syncthreads();                        // all gathers done -> safe to overwrite u_s
    float inv_s = 1.f/(sqrtf(nprev) + 1e-12f);
    float local = 0.f;
    #pragma unroll
    for (int it = 0; it < 30; ++it){
      int m = tid + it*1024;
      if (m < Mn){
        if (!fin){
          float o = inv_s*wreg[it];
          local += o*o;
          u_s[m] = o;
        } else {
          local += u_s[m]*wreg[it];         // Rayleigh numerator: u . (L u)
        }
      }
    }
    #pragma unroll
    for (int o2 = 1; o2 < 64; o2 <<= 1) local += __shfl_xor(local, o2);
    if ((tid & 63) == 0) redw[tid >> 6] = local;
    __syncthreads();
    if (tid == 0){
      float tot = 0.f;
      #pragma unroll
      for (int q = 0; q < 16; ++q) tot += redw[q];
      if (!fin) nprev = tot;                // ||u_r||^2
      else {
        float nn = sqrtf(nprev) + 1e-12f;   // ||u_75||
        float lam = tot/(nn*nn);
        lamc[2*t+0] = -2.f/lam;
        lamc[2*t+1] =  2.f/lam - 1.f;
      }
    }
    __syncthreads();                        // nprev visible before next round
  }
}

// ---------------------------------------------------------------- Chebyshev SpMM (wave per row, lane = channel, XCD-swizzled)
__global__ __launch_bounds__(256) void k_cheb(const __hip_bfloat16* __restrict__ xin,
    const __hip_bfloat16* __restrict__ xb0, __hip_bfloat16* __restrict__ outp,
    const int* __restrict__ rp, const unsigned short* __restrict__ col,
    const float* __restrict__ dinv, const float* __restrict__ lamc, float s1, float s2)
{
  const int blk = blockIdx.x;               // 90000 = 8*11250
  const int w = (blk & 7)*11250 + (blk >> 3);
  const int gw = w*4 + (threadIdx.x >> 6);
  const int lane = threadIdx.x & 63;
  int t = gw / Mn, m = gw - t*Mn;
  float coef = lamc[2*t], diag = lamc[2*t+1];
  const __hip_bfloat16* xt = xin + (size_t)t*Mn*Hh;
  const float* dv = dinv + t*Mn;
  float acc = diag * bf2f(xt[(size_t)m*Hh + lane]);
  float cdm = coef * dv[m];
  int bgn = rp[t*(Mn+1)+m], end = rp[t*(Mn+1)+m+1];
  const unsigned short* cp = col + (size_t)t*Ee;
  int i = bgn;
  for (; i < end && (i & 3); ++i){ int c = cp[i]; acc += (cdm*dv[c])*bf2f(xt[(size_t)c*Hh + lane]); }
  for (; i + 4 <= end; i += 4){
    ushort4 c4 = *(const ushort4*)(cp + i);
    float w0 = cdm*dv[c4.x], w1 = cdm*dv[c4.y], w2 = cdm*dv[c4.z], w3 = cdm*dv[c4.w];
    acc += w0*bf2f(xt[(size_t)c4.x*Hh + lane]);
    acc += w1*bf2f(xt[(size_t)c4.y*Hh + lane]);
    acc += w2*bf2f(xt[(size_t)c4.z*Hh + lane]);
    acc += w3*bf2f(xt[(size_t)c4.w*Hh + lane]);
  }
  for (; i < end; ++i){ int c = cp[i]; acc += (cdm*dv[c])*bf2f(xt[(size_t)c*Hh + lane]); }
  float o = s1*acc;
  if (s2 != 0.f) o += s2*bf2f(xb0[(size_t)gw*Hh + lane]);
  outp[(size_t)gw*Hh + lane] = f2bf(o);
}

// ---------------------------------------------------------------- fold cheb_W into conv_W
__global__ void k_ww(const float* __restrict__ chebW, const float* __restrict__ chebb,
    const float* __restrict__ convW, const float* __restrict__ convb, float* __restrict__ WW, float* __restrict__ c0)
{
  int idx = blockIdx.x*256 + threadIdx.x;
  if (idx < 3*Tt*Hh*Oo){
    int oc = idx % Oo; int j = (idx/Oo) % Hh; int t = (idx/(Oo*Hh)) % Tt; int i = idx/(Oo*Hh*Tt);
    const float* cw = chebW + ((size_t)i*Hh + j)*HC + (HC-KW);
    const float* vw = convW + ((size_t)oc*Tt + t)*KW;
    float s = 0.f;
    for (int k = 0; k < KW; ++k) s += cw[k]*vw[k];
    WW[idx] = s;
  }
  if (blockIdx.x == 0 && threadIdx.x < Oo){
    int oc = threadIdx.x;
    float s = convb[oc];
    for (int t = 0; t < Tt; ++t){
      const float* vw = convW + ((size_t)oc*Tt + t)*KW;
      for (int k = 0; k < KW; ++k) s += chebb[(HC-KW)+k]*vw[k];
    }
    c0[oc] = s;
  }
}

// ---------------------------------------------------------------- fused cheb-GEMM + temporal conv + sigmoid
__global__ __launch_bounds__(256) void k_final(const __hip_bfloat16* __restrict__ tx0,
    const __hip_bfloat16* __restrict__ tx1, const __hip_bfloat16* __restrict__ tx2,
    const float* __restrict__ WW, const float* __restrict__ c0, float* __restrict__ outp)
{
  __shared__ float xs[64][65];
  __shared__ float ww[64][12];
  const int tid = threadIdx.x;
  const int n0 = blockIdx.x*64;
  const int n = tid & 63, ob = (tid >> 6)*3;
  float acc[3] = {0.f, 0.f, 0.f};
  for (int it = 0; it < 3*Tt; ++it){
    int ii = it / Tt, t = it % Tt;
    const __hip_bfloat16* tx = (ii == 0) ? tx0 : (ii == 1) ? tx1 : tx2;
    __syncthreads();
    for (int idx = tid; idx < 64*64; idx += 256){
      int mm = idx >> 6, j = idx & 63;
      int m = n0 + mm;
      xs[mm][j] = (m < Mn) ? bf2f(tx[((size_t)t*Mn + m)*Hh + j]) : 0.f;
    }
    for (int idx = tid; idx < 64*Oo; idx += 256)
      ((float*)ww)[idx] = WW[((size_t)(ii*Tt + t)*Hh)*Oo + idx];
    __syncthreads();
    #pragma unroll 8
    for (int j = 0; j < 64; ++j){
      float x = xs[n][j];
      acc[0] += x*ww[j][ob+0];
      acc[1] += x*ww[j][ob+1];
      acc[2] += x*ww[j][ob+2];
    }
  }
  int m = n0 + n;
  if (m < Mn){
    #pragma unroll
    for (int q = 0; q < 3; ++q) outp[(size_t)m*Oo + ob + q] = sigm(acc[q] + c0[ob+q]);
  }
}

// ================================================================ host
extern "C" void kernel_launch(void* const* d_in, const int* in_sizes, int n_in,
                              void* d_out, int out_size, void* d_ws, size_t ws_size,
                              hipStream_t stream)
{
  const float* nf    = (const float*)d_in[0];
  const int*   ei    = (const int*)d_in[1];
  const float* Wih0  = (const float*)d_in[2];
  const float* Whh0  = (const float*)d_in[3];
  const float* bih0  = (const float*)d_in[4];
  const float* bhh0  = (const float*)d_in[5];
  const float* Wih1  = (const float*)d_in[6];
  const float* Whh1  = (const float*)d_in[7];
  const float* bih1  = (const float*)d_in[8];
  const float* bhh1  = (const float*)d_in[9];
  const float* lns   = (const float*)d_in[10];
  const float* lnb   = (const float*)d_in[11];
  const float* chebW = (const float*)d_in[12];
  const float* chebb = (const float*)d_in[13];
  const float* convW = (const float*)d_in[14];
  const float* convb = (const float*)d_in[15];
  float* outp = (float*)d_out;

  char* base = (char*)d_ws;
  size_t off = 0;
  auto alloc = [&](size_t bytes)->char*{ char* p = base + off; off += (bytes + 255) & ~(size_t)255; return p; };

  __hip_bfloat16* y0  = (__hip_bfloat16*)alloc((size_t)Tt*Mn*C2*2);
  __hip_bfloat16* tx1 = y0;
  __hip_bfloat16* tx2 = y0 + (size_t)Tt*Mn*Hh;
  __hip_bfloat16* gi  = (__hip_bfloat16*)alloc((size_t)Tt*Mn*Gg*2);
  unsigned* pair = (unsigned*)gi;          // overlaps gi: pair dead before k_gi1m writes gi
  __hip_bfloat16* xbt = (__hip_bfloat16*)alloc((size_t)Tt*Mn*Hh*2);
  unsigned short* col16 = (unsigned short*)alloc((size_t)Tt*Ee*2);
  int*   deg  = (int*)alloc((size_t)Tt*Mn*4);
  int*   rp   = (int*)alloc((size_t)Tt*(Mn+1)*4);
  int*   bcnt = (int*)alloc((size_t)Tt*NB*4);
  int*   bfill= (int*)alloc((size_t)Tt*NB*4);
  int*   rpb  = (int*)alloc((size_t)Tt*(NB+1)*4);
  float* dinv = (float*)alloc((size_t)Tt*Mn*4);
  float* lamc = (float*)alloc((size_t)2*Tt*4);
  float* WW   = (float*)alloc((size_t)3*Tt*Hh*Oo*4);
  float* c0   = (float*)alloc((size_t)Oo*4);
  __hip_bfloat16* Wbf = (__hip_bfloat16*)alloc((size_t)Gg*C2*2);
  (void)ws_size; (void)in_sizes; (void)n_in; (void)out_size;

  // CSR build: bucket histogram -> bucket scan -> partition -> per-bucket counting sort (emits rp+deg)
  k_init<<<(Tt*NB + 255)/256, 256, 0, stream>>>(bcnt, bfill);
  k_bcnt<<<Tt*BPT, 256, 0, stream>>>(ei, bcnt);
  k_bscan<<<Tt, 256, 0, stream>>>(bcnt, rpb);
  k_part2<<<Tt*BPT, 256, 0, stream>>>(ei, rpb, bfill, pair);
  k_csr2<<<Tt*NB, 256, 0, stream>>>(rpb, pair, col16, rp, deg);
  k_dinv<<<(Tt*Mn + 255)/256, 256, 0, stream>>>(deg, dinv);

  // GRU stack (layer-1 forward direction is dead code -> skipped)
  k_wcvt<<<(Gg*C2 + 255)/256, 256, 0, stream>>>(Wih1 + (size_t)Gg*C2, Wbf);
  k_gru0<<<(Mn + 31)/32, 256, 0, stream>>>(nf, Wih0, Whh0, bih0, bhh0, y0);
  {
    int waves = Tt*((Mn + 31)/32);
    k_gi1m<<<(waves + 3)/4, 256, 0, stream>>>(y0, Wbf, bih1 + Gg, gi);
  }
  k_gru1r<<<(Mn + 31)/32, 256, 0, stream>>>(gi, Whh1 + (size_t)Gg*Hh, bhh1 + Gg, lns, lnb, xbt);

  // power iteration: one block per t, u resident in LDS, single ordinary dispatch
  k_pitc2<<<Tt, 1024, 0, stream>>>(rp, col16, lamc);

  // Chebyshev: tx1 = Lhat(x), tx2 = 2*Lhat(tx1) - x
  k_cheb<<<(Tt*Mn)/4, 256, 0, stream>>>(xbt, xbt, tx1, rp, col16, dinv, lamc, 1.f, 0.f);
  k_cheb<<<(Tt*Mn)/4, 256, 0, stream>>>(tx1, xbt, tx2, rp, col16, dinv, lamc, 2.f, -1.f);

  // folded cheb-GEMM + conv + sigmoid
  k_ww<<<(3*Tt*Hh*Oo + 255)/256, 256, 0, stream>>>(chebW, chebb, convW, convb, WW, c0);
  k_final<<<(Mn + 63)/64, 256, 0, stream>>>(xbt, tx1, tx2, WW, c0, outp);
}

// Round 9
// 3247.617 us; speedup vs baseline: 4.6277x; 4.6277x over previous
//
#include <hip/hip_runtime.h>
#include <hip/hip_bf16.h>

#define DEV __device__ __forceinline__

constexpr int Mn  = 30000;   // nodes (B=1)
constexpr int Tt  = 12;
constexpr int CIN = 16;
constexpr int Hh  = 64;
constexpr int Gg  = 192;     // 3H
constexpr int C2  = 128;     // 2H
constexpr int Ee  = 960000;  // edges per timestep (bidirectional)
constexpr int HC  = 128;
constexpr int Oo  = 12;
constexpr int KW  = 128;
constexpr int HP  = 72;      // padded h row stride (floats)
constexpr int NB  = 235;     // 128-row buckets per t (235*128 >= 30000)
constexpr int EPB = 8192;    // edges per block for bcnt/part2
constexpr int BPT = 118;     // ceil(Ee/EPB)
constexpr int CHK = 21;      // chunks per t for k_pit3 (252 blocks total)
constexpr int RC  = 1429;    // rows per chunk (21*1429 >= 30000)

DEV float bf2f(__hip_bfloat16 v){ return __bfloat162float(v); }
DEV __hip_bfloat16 f2bf(float v){ return __float2bfloat16(v); }
DEV float sigm(float x){ return __builtin_amdgcn_rcpf(1.f + __expf(-x)); }
DEV float tanh_f(float x){ return 1.f - 2.f*__builtin_amdgcn_rcpf(__expf(2.f*x) + 1.f); }

typedef short bfrag8 __attribute__((ext_vector_type(8)));
typedef float ffrag4 __attribute__((ext_vector_type(4)));

// ---------------------------------------------------------------- init
__global__ void k_init(float* nrm2, float* dotb, float* u0, int* bcnt, int* bfill){
  int i = blockIdx.x*256 + threadIdx.x;
  if (i < Tt*Mn) u0[i] = 0.005773502691896258f;    // 1/sqrt(30000)
  if (i < 76*Tt) nrm2[i] = (i < Tt) ? 1.0f : 0.0f;
  if (i < Tt) dotb[i] = 0.f;
  if (i < Tt*NB){ bcnt[i] = 0; bfill[i] = 0; }
}

// ---------------------------------------------------------------- stage 1: block-aggregated bucket histogram
__global__ __launch_bounds__(256) void k_bcnt(const int* __restrict__ ei, int* __restrict__ bcnt){
  __shared__ int h[NB];
  const int b = blockIdx.x;                 // 1416 = 8*177
  const int w = (b & 7)*177 + (b >> 3);
  const int t = w / BPT, ch = w - t*BPT;
  const int e0 = ch*EPB;
  const int tid = threadIdx.x;
  for (int i = tid; i < NB; i += 256) h[i] = 0;
  __syncthreads();
  #pragma unroll
  for (int i = 0; i < 32; ++i){
    int e = e0 + i*256 + tid;
    if (e < Ee){
      int r = ei[(size_t)(t*2)*Ee + e];
      atomicAdd(&h[r >> 7], 1);
    }
  }
  __syncthreads();
  for (int i = tid; i < NB; i += 256){
    int c = h[i];
    if (c > 0) atomicAdd(&bcnt[t*NB + i], c);
  }
}

// ---------------------------------------------------------------- stage 2: per-t exclusive scan of bucket counts
__global__ __launch_bounds__(256) void k_bscan(const int* __restrict__ bcnt, int* __restrict__ rpb){
  int t = blockIdx.x, tid = threadIdx.x;
  __shared__ int ps[256];
  int v = (tid < NB) ? bcnt[t*NB + tid] : 0;
  ps[tid] = v;
  __syncthreads();
  for (int o = 1; o < 256; o <<= 1){
    int x = (tid >= o) ? ps[tid-o] : 0;
    __syncthreads();
    ps[tid] += x;
    __syncthreads();
  }
  if (tid < NB) rpb[t*(NB+1) + tid] = ps[tid] - v;
  if (tid == 255) rpb[t*(NB+1) + NB] = ps[NB-1];
}

// ---------------------------------------------------------------- stage 3: partition edges into buckets (block-aggregated reservations)
__global__ __launch_bounds__(256) void k_part2(const int* __restrict__ ei, const int* __restrict__ rpb,
    int* __restrict__ bfill, unsigned* __restrict__ pair){
  __shared__ int hcnt[NB];
  __shared__ int hbase[NB];
  const int b = blockIdx.x;                 // 1416 = 8*177
  const int w = (b & 7)*177 + (b >> 3);
  const int t = w / BPT, ch = w - t*BPT;
  const int e0 = ch*EPB;
  const int tid = threadIdx.x;
  for (int i = tid; i < NB; i += 256) hcnt[i] = 0;
  __syncthreads();
  unsigned key[32];
  #pragma unroll
  for (int i = 0; i < 32; ++i){
    int e = e0 + i*256 + tid;
    unsigned k = 0xFFFFFFFFu;
    if (e < Ee){
      int r = ei[(size_t)(t*2)*Ee + e];
      int c = ei[(size_t)(t*2+1)*Ee + e];
      k = ((unsigned)r << 16) | (unsigned)c;
      atomicAdd(&hcnt[r >> 7], 1);
    }
    key[i] = k;
  }
  __syncthreads();
  for (int i = tid; i < NB; i += 256){
    int cnt = hcnt[i];
    int base = (cnt > 0) ? atomicAdd(&bfill[t*NB + i], cnt) : 0;
    hbase[i] = rpb[t*(NB+1) + i] + base;
  }
  __syncthreads();
  for (int i = tid; i < NB; i += 256) hcnt[i] = 0;
  __syncthreads();
  #pragma unroll
  for (int i = 0; i < 32; ++i){
    unsigned k = key[i];
    if (k != 0xFFFFFFFFu){
      int r = (int)(k >> 16);
      int bk = r >> 7;
      int pos = atomicAdd(&hcnt[bk], 1);
      pair[(size_t)t*Ee + hbase[bk] + pos] = ((unsigned)(r & 127) << 16) | (k & 0xFFFFu);
    }
  }
}

// ---------------------------------------------------------------- stage 4: per-bucket LDS counting sort -> col16, rp, deg
__global__ __launch_bounds__(256) void k_csr2(const int* __restrict__ rpb, const unsigned* __restrict__ pair,
    unsigned short* __restrict__ col16, int* __restrict__ rp, int* __restrict__ deg){
  __shared__ unsigned short cols_s[9216];
  __shared__ int lcnt[128], lfill[128];
  __shared__ int ps[256];
  const int blk = blockIdx.x;               // Tt*NB
  const int t = blk / NB, bk = blk - t*NB;
  const int r0 = bk << 7;
  const int nr = (r0 + 128 <= Mn) ? 128 : (Mn - r0);
  const int base = rpb[t*(NB+1) + bk];
  const int cnt  = rpb[t*(NB+1) + bk + 1] - base;
  const int tid = threadIdx.x;
  if (tid < 128) lcnt[tid] = 0;
  __syncthreads();
  for (int i = tid; i < cnt; i += 256){
    unsigned v = pair[(size_t)t*Ee + base + i];
    atomicAdd(&lcnt[v >> 16], 1);
  }
  __syncthreads();
  int v2 = (tid < 128) ? lcnt[tid] : 0;
  ps[tid] = v2;
  __syncthreads();
  for (int o = 1; o < 128; o <<= 1){
    int x = (tid >= o) ? ps[tid-o] : 0;
    __syncthreads();
    ps[tid] += x;
    __syncthreads();
  }
  if (tid < 128){
    int excl = ps[tid] - v2;
    lfill[tid] = excl;
    if (tid < nr){
      rp[t*(Mn+1) + r0 + tid] = base + excl;
      deg[t*Mn + r0 + tid] = v2;
    }
  }
  if (bk == NB-1 && tid == 0) rp[t*(Mn+1) + Mn] = base + cnt;
  __syncthreads();
  for (int i = tid; i < cnt; i += 256){
    unsigned v = pair[(size_t)t*Ee + base + i];
    int pos = atomicAdd(&lfill[v >> 16], 1);
    cols_s[pos] = (unsigned short)(v & 0xFFFFu);
  }
  __syncthreads();
  for (int i = tid; i < cnt; i += 256)
    col16[(size_t)t*Ee + base + i] = cols_s[i];
}

// ---------------------------------------------------------------- dinv
__global__ void k_dinv(const int* __restrict__ deg, float* __restrict__ dinv){
  int i = blockIdx.x*256 + threadIdx.x;
  if (i < Tt*Mn){ int d = deg[i]; dinv[i] = (d > 0) ? rsqrtf((float)d) : 0.f; }
}

// ---------------------------------------------------------------- GRU layer 0 (both dirs), writes y0 (T,M,128) bf16
__global__ __launch_bounds__(256) void k_gru0(
    const float* __restrict__ nf, const float* __restrict__ Wih, const float* __restrict__ Whh,
    const float* __restrict__ bih, const float* __restrict__ bhh, __hip_bfloat16* __restrict__ y0)
{
  __shared__ float xs[Tt][CIN][32];
  __shared__ __hip_bfloat16 wi[CIN][Gg];
  __shared__ __hip_bfloat16 wh[Hh][Gg];
  __shared__ float hb[32][HP];
  __shared__ float bi[Gg], bh[Gg];
  const int tid = threadIdx.x;
  const int m0  = blockIdx.x*32;
  for (int idx = tid; idx < Tt*32*CIN; idx += 256){
    int t = idx / (32*CIN); int rr = (idx / CIN) & 31; int k = idx & (CIN-1);
    int m = m0 + rr;
    xs[t][k][rr] = (m < Mn) ? nf[((size_t)t*Mn + m)*CIN + k] : 0.f;
  }
  const int jg = tid & 31, rg = tid >> 5;
  const int j0 = jg*2, rg4 = rg*4;
  for (int d = 0; d < 2; ++d){
    __syncthreads();
    for (int idx = tid; idx < Gg*CIN; idx += 256){
      int g = idx / CIN, k = idx & (CIN-1);
      wi[k][g] = f2bf(Wih[((size_t)d*Gg + g)*CIN + k]);
    }
    for (int idx = tid; idx < Gg*Hh; idx += 256){
      int g = idx >> 6, k = idx & 63;
      wh[k][g] = f2bf(Whh[((size_t)d*Gg + g)*Hh + k]);
    }
    if (tid < Gg){ bi[tid] = bih[d*Gg + tid]; bh[tid] = bhh[d*Gg + tid]; }
    for (int idx = tid; idx < 32*HP; idx += 256) ((float*)hb)[idx] = 0.f;
    __syncthreads();
    for (int step = 0; step < Tt; ++step){
      int t = d ? (Tt-1-step) : step;
      float ar[4][2], az[4][2], ai[4][2], ah[4][2];
      #pragma unroll
      for (int i = 0; i < 4; ++i){
        #pragma unroll
        for (int jj = 0; jj < 2; ++jj){
          int j = j0 + jj;
          ar[i][jj] = bi[j] + bh[j];
          az[i][jj] = bi[Hh+j] + bh[Hh+j];
          ai[i][jj] = bi[2*Hh+j];
          ah[i][jj] = bh[2*Hh+j];
        }
      }
      #pragma unroll
      for (int k = 0; k < CIN; ++k){
        float4 xv4 = *(const float4*)&xs[t][k][rg4];
        float xv[4] = {xv4.x, xv4.y, xv4.z, xv4.w};
        __hip_bfloat162 pr = *(const __hip_bfloat162*)&wi[k][j0];
        __hip_bfloat162 pz = *(const __hip_bfloat162*)&wi[k][Hh+j0];
        __hip_bfloat162 pn = *(const __hip_bfloat162*)&wi[k][2*Hh+j0];
        float wr[2] = {bf2f(pr.x), bf2f(pr.y)};
        float wz[2] = {bf2f(pz.x), bf2f(pz.y)};
        float wn[2] = {bf2f(pn.x), bf2f(pn.y)};
        #pragma unroll
        for (int i = 0; i < 4; ++i){
          #pragma unroll
          for (int jj = 0; jj < 2; ++jj){
            ar[i][jj] += xv[i]*wr[jj];
            az[i][jj] += xv[i]*wz[jj];
            ai[i][jj] += xv[i]*wn[jj];
          }
        }
      }
      #pragma unroll 4
      for (int k4 = 0; k4 < 16; ++k4){
        float4 h0 = *(const float4*)&hb[rg4+0][k4*4];
        float4 h1 = *(const float4*)&hb[rg4+1][k4*4];
        float4 h2 = *(const float4*)&hb[rg4+2][k4*4];
        float4 h3 = *(const float4*)&hb[rg4+3][k4*4];
        #pragma unroll
        for (int kk = 0; kk < 4; ++kk){
          int k = k4*4 + kk;
          float hv[4] = { ((const float*)&h0)[kk], ((const float*)&h1)[kk],
                          ((const float*)&h2)[kk], ((const float*)&h3)[kk] };
          __hip_bfloat162 pr = *(const __hip_bfloat162*)&wh[k][j0];
          __hip_bfloat162 pz = *(const __hip_bfloat162*)&wh[k][Hh+j0];
          __hip_bfloat162 pn = *(const __hip_bfloat162*)&wh[k][2*Hh+j0];
          float wr[2] = {bf2f(pr.x), bf2f(pr.y)};
          float wz[2] = {bf2f(pz.x), bf2f(pz.y)};
          float wn[2] = {bf2f(pn.x), bf2f(pn.y)};
          #pragma unroll
          for (int i = 0; i < 4; ++i){
            #pragma unroll
            for (int jj = 0; jj < 2; ++jj){
              ar[i][jj] += hv[i]*wr[jj];
              az[i][jj] += hv[i]*wz[jj];
              ah[i][jj] += hv[i]*wn[jj];
            }
          }
        }
      }
      __syncthreads();
      #pragma unroll
      for (int i = 0; i < 4; ++i){
        int r = rg4 + i; int m = m0 + r;
        float hn2[2];
        #pragma unroll
        for (int jj = 0; jj < 2; ++jj){
          float rr = sigm(ar[i][jj]);
          float zz = sigm(az[i][jj]);
          float nn = tanh_f(ai[i][jj] + rr*ah[i][jj]);
          float hv = hb[r][j0+jj];
          hn2[jj] = (1.f-zz)*nn + zz*hv;
          hb[r][j0+jj] = hn2[jj];
        }
        if (m < Mn){
          __hip_bfloat162 pk; pk.x = f2bf(hn2[0]); pk.y = f2bf(hn2[1]);
          *(__hip_bfloat162*)&y0[((size_t)t*Mn + m)*C2 + d*Hh + j0] = pk;
        }
      }
      __syncthreads();
    }
  }
}

// ---------------------------------------------------------------- convert layer-1 reverse weights to bf16
__global__ void k_wcvt(const float* __restrict__ W, __hip_bfloat16* __restrict__ Wbf){
  int i = blockIdx.x*256 + threadIdx.x;
  if (i < Gg*C2) Wbf[i] = f2bf(W[i]);
}

// ---------------------------------------------------------------- layer-1 input projection via MFMA
__global__ __launch_bounds__(256) void k_gi1m(const __hip_bfloat16* __restrict__ y0,
    const __hip_bfloat16* __restrict__ Wbf, const float* __restrict__ bih, __hip_bfloat16* __restrict__ gi)
{
  const int wid  = (blockIdx.x*256 + threadIdx.x) >> 6;
  const int lane = threadIdx.x & 63;
  const int SEGS = (Mn + 31)/32;
  if (wid >= Tt*SEGS) return;
  const int t = wid / SEGS, seg = wid - t*SEGS;
  const int m0 = seg*32;
  const int lr = lane & 15, lq = lane >> 4;
  const __hip_bfloat16* yb = y0 + (size_t)t*Mn*C2;

  ffrag4 acc[2][12];
  #pragma unroll
  for (int i = 0; i < 2; ++i){
    #pragma unroll
    for (int n = 0; n < 12; ++n) acc[i][n] = (ffrag4){0.f,0.f,0.f,0.f};
  }
  #pragma unroll
  for (int ks = 0; ks < 4; ++ks){
    const int ko = ks*32 + lq*8;
    bfrag8 a0 = *(const bfrag8*)(yb + (size_t)(m0 + lr     )*C2 + ko);
    bfrag8 a1 = *(const bfrag8*)(yb + (size_t)(m0 + 16 + lr)*C2 + ko);
    #pragma unroll
    for (int nt = 0; nt < 12; ++nt){
      bfrag8 b = *(const bfrag8*)(Wbf + (size_t)(nt*16 + lr)*C2 + ko);
      acc[0][nt] = __builtin_amdgcn_mfma_f32_16x16x32_bf16(a0, b, acc[0][nt], 0, 0, 0);
      acc[1][nt] = __builtin_amdgcn_mfma_f32_16x16x32_bf16(a1, b, acc[1][nt], 0, 0, 0);
    }
  }
  #pragma unroll
  for (int nt = 0; nt < 12; ++nt){
    int g = nt*16 + lr;
    float bb = bih[g];
    #pragma unroll
    for (int r = 0; r < 4; ++r){
      int mm0 = m0 + lq*4 + r;
      int mm1 = mm0 + 16;
      if (mm0 < Mn) gi[((size_t)t*Mn + mm0)*Gg + g] = f2bf(acc[0][nt][r] + bb);
      if (mm1 < Mn) gi[((size_t)t*Mn + mm1)*Gg + g] = f2bf(acc[1][nt][r] + bb);
    }
  }
}

// ---------------------------------------------------------------- GRU layer 1 (reverse only) + fused LayerNorm
__global__ __launch_bounds__(256) void k_gru1r(const __hip_bfloat16* __restrict__ gi,
    const float* __restrict__ Whh, const float* __restrict__ bhh,
    const float* __restrict__ lns, const float* __restrict__ lnb,
    __hip_bfloat16* __restrict__ xbt)
{
  __shared__ __hip_bfloat16 wh[Hh][Gg];
  __shared__ float hb[32][HP];
  __shared__ float bh[Gg];
  __shared__ float sc[Hh], bs[Hh];
  const int tid = threadIdx.x;
  const int m0  = blockIdx.x*32;
  for (int idx = tid; idx < Gg*Hh; idx += 256){
    int g = idx >> 6, k = idx & 63;
    wh[k][g] = f2bf(Whh[(size_t)g*Hh + k]);
  }
  if (tid < Gg) bh[tid] = bhh[tid];
  if (tid < Hh){ sc[tid] = lns[tid]; bs[tid] = lnb[tid]; }
  for (int idx = tid; idx < 32*HP; idx += 256) ((float*)hb)[idx] = 0.f;
  __syncthreads();
  const int jg = tid & 31, rg = tid >> 5;
  const int j0 = jg*2, rg4 = rg*4;
  for (int step = 0; step < Tt; ++step){
    int t = Tt-1-step;
    float ar[4][2], az[4][2], ai[4][2], ah[4][2];
    #pragma unroll
    for (int i = 0; i < 4; ++i){
      int m = m0 + rg4 + i;
      int mc = (m < Mn) ? m : 0;
      const __hip_bfloat16* gp = gi + ((size_t)t*Mn + mc)*Gg;
      __hip_bfloat162 pr = *(const __hip_bfloat162*)&gp[j0];
      __hip_bfloat162 pz = *(const __hip_bfloat162*)&gp[Hh+j0];
      __hip_bfloat162 pn = *(const __hip_bfloat162*)&gp[2*Hh+j0];
      #pragma unroll
      for (int jj = 0; jj < 2; ++jj){
        int j = j0 + jj;
        float gr = jj ? bf2f(pr.y) : bf2f(pr.x);
        float gz = jj ? bf2f(pz.y) : bf2f(pz.x);
        float gn = jj ? bf2f(pn.y) : bf2f(pn.x);
        ar[i][jj] = gr + bh[j];
        az[i][jj] = gz + bh[Hh+j];
        ai[i][jj] = gn;
        ah[i][jj] = bh[2*Hh+j];
      }
    }
    #pragma unroll 4
    for (int k4 = 0; k4 < 16; ++k4){
      float4 h0 = *(const float4*)&hb[rg4+0][k4*4];
      float4 h1 = *(const float4*)&hb[rg4+1][k4*4];
      float4 h2 = *(const float4*)&hb[rg4+2][k4*4];
      float4 h3 = *(const float4*)&hb[rg4+3][k4*4];
      #pragma unroll
      for (int kk = 0; kk < 4; ++kk){
        int k = k4*4 + kk;
        float hv[4] = { ((const float*)&h0)[kk], ((const float*)&h1)[kk],
                        ((const float*)&h2)[kk], ((const float*)&h3)[kk] };
        __hip_bfloat162 pr = *(const __hip_bfloat162*)&wh[k][j0];
        __hip_bfloat162 pz = *(const __hip_bfloat162*)&wh[k][Hh+j0];
        __hip_bfloat162 pn = *(const __hip_bfloat162*)&wh[k][2*Hh+j0];
        float wr[2] = {bf2f(pr.x), bf2f(pr.y)};
        float wz[2] = {bf2f(pz.x), bf2f(pz.y)};
        float wn[2] = {bf2f(pn.x), bf2f(pn.y)};
        #pragma unroll
        for (int i = 0; i < 4; ++i){
          #pragma unroll
          for (int jj = 0; jj < 2; ++jj){
            ar[i][jj] += hv[i]*wr[jj];
            az[i][jj] += hv[i]*wz[jj];
            ah[i][jj] += hv[i]*wn[jj];
          }
        }
      }
    }
    __syncthreads();
    #pragma unroll
    for (int i = 0; i < 4; ++i){
      int r = rg4 + i;
      #pragma unroll
      for (int jj = 0; jj < 2; ++jj){
        float rr = sigm(ar[i][jj]);
        float zz = sigm(az[i][jj]);
        float nn = tanh_f(ai[i][jj] + rr*ah[i][jj]);
        float hv = hb[r][j0+jj];
        hb[r][j0+jj] = (1.f-zz)*nn + zz*hv;
      }
    }
    __syncthreads();
    {
      int r = tid >> 3, l = tid & 7;
      float vals[8];
      float s1 = 0.f, s2 = 0.f;
      #pragma unroll
      for (int q = 0; q < 8; ++q){ float v = hb[r][l + 8*q]; vals[q] = v; s1 += v; s2 += v*v; }
      #pragma unroll
      for (int off = 1; off <= 4; off <<= 1){ s1 += __shfl_xor(s1, off); s2 += __shfl_xor(s2, off); }
      float mu  = s1 * (1.f/64.f);
      float var = s2 * (1.f/64.f) - mu*mu;
      float rs  = rsqrtf(var + 1e-5f);
      int m = m0 + r;
      if (m < Mn){
        __hip_bfloat16* op = xbt + ((size_t)t*Mn + m)*Hh;
        #pragma unroll
        for (int q = 0; q < 8; ++q){ int j = l + 8*q; op[j] = f2bf((vals[q]-mu)*rs*sc[j] + bs[j]); }
      }
    }
    __syncthreads();
  }
}

// ---------------------------------------------------------------- one power-iteration round: full u_t staged in LDS (120 KB),
// single unmasked pass, 21 blocks per t. Deferred normalization as validated R2-R6.
__global__ __launch_bounds__(1024) void k_pit3(const int* __restrict__ rp,
    const unsigned short* __restrict__ col, const float* __restrict__ uin, float* __restrict__ uout,
    const float* __restrict__ nrm2p, float* __restrict__ nrm2o, float* __restrict__ dotb, int fin)
{
  __shared__ float u_s[Mn];                 // 120000 B
  __shared__ float redw[16];
  const int b = blockIdx.x;                 // Tt*CHK = 252
  const int t = b / CHK, ch = b - t*CHK;
  const int r0 = ch*RC;
  const int r1 = (r0 + RC < Mn) ? r0 + RC : Mn;
  const int tid = threadIdx.x;
  const float* ut = uin + t*Mn;
  const int* rpt = rp + t*(Mn+1);
  const unsigned short* cp = col + (size_t)t*Ee;
  // stage full u_t (float4, coalesced)
  for (int i = tid; i < Mn/4; i += 1024) ((float4*)u_s)[i] = ((const float4*)ut)[i];
  __syncthreads();
  float inv_s = fin ? 1.f : 1.f/(sqrtf(nrm2p[t]) + 1e-12f);
  float local = 0.f;
  for (int m = r0 + tid; m < r1; m += 1024){
    int bgn = rpt[m], end = rpt[m+1];
    float s = 0.f;
    int i = bgn;
    for (; i < end && (i & 3); ++i) s += u_s[cp[i]];
    for (; i + 4 <= end; i += 4){
      ushort4 c4 = *(const ushort4*)(cp + i);
      s += (u_s[c4.x] + u_s[c4.y]) + (u_s[c4.z] + u_s[c4.w]);
    }
    for (; i < end; ++i) s += u_s[cp[i]];
    float uv = u_s[m];
    float wv = (float)(end - bgn)*uv - s;
    if (!fin){ float o = inv_s*wv; uout[t*Mn+m] = o; local += o*o; }
    else local += uv*wv;
  }
  #pragma unroll
  for (int o2 = 1; o2 < 64; o2 <<= 1) local += __shfl_xor(local, o2);
  if ((tid & 63) == 0) redw[tid >> 6] = local;
  __syncthreads();
  if (tid == 0){
    float tot = 0.f;
    #pragma unroll
    for (int q = 0; q < 16; ++q) tot += redw[q];
    atomicAdd(fin ? &dotb[t] : &nrm2o[t], tot);
  }
}

__global__ void k_lamfin(const float* __restrict__ nrm2, const float* __restrict__ dotb, float* __restrict__ lamc){
  int t = threadIdx.x;
  if (t < Tt){
    float nn = sqrtf(nrm2[75*Tt + t]) + 1e-12f;
    float lam = dotb[t] / (nn*nn);
    lamc[2*t+0] = -2.f/lam;
    lamc[2*t+1] =  2.f/lam - 1.f;
  }
}

// ---------------------------------------------------------------- Chebyshev SpMM (wave per row, lane = channel, XCD-swizzled)
__global__ __launch_bounds__(256) void k_cheb(const __hip_bfloat16* __restrict__ xin,
    const __hip_bfloat16* __restrict__ xb0, __hip_bfloat16* __restrict__ outp,
    const int* __restrict__ rp, const unsigned short* __restrict__ col,
    const float* __restrict__ dinv, const float* __restrict__ lamc, float s1, float s2)
{
  const int blk = blockIdx.x;               // 90000 = 8*11250
  const int w = (blk & 7)*11250 + (blk >> 3);
  const int gw = w*4 + (threadIdx.x >> 6);
  const int lane = threadIdx.x & 63;
  int t = gw / Mn, m = gw - t*Mn;
  float coef = lamc[2*t], diag = lamc[2*t+1];
  const __hip_bfloat16* xt = xin + (size_t)t*Mn*Hh;
  const float* dv = dinv + t*Mn;
  float acc = diag * bf2f(xt[(size_t)m*Hh + lane]);
  float cdm = coef * dv[m];
  int bgn = rp[t*(Mn+1)+m], end = rp[t*(Mn+1)+m+1];
  const unsigned short* cp = col + (size_t)t*Ee;
  int i = bgn;
  for (; i < end && (i & 3); ++i){ int c = cp[i]; acc += (cdm*dv[c])*bf2f(xt[(size_t)c*Hh + lane]); }
  for (; i + 4 <= end; i += 4){
    ushort4 c4 = *(const ushort4*)(cp + i);
    float w0 = cdm*dv[c4.x], w1 = cdm*dv[c4.y], w2 = cdm*dv[c4.z], w3 = cdm*dv[c4.w];
    acc += w0*bf2f(xt[(size_t)c4.x*Hh + lane]);
    acc += w1*bf2f(xt[(size_t)c4.y*Hh + lane]);
    acc += w2*bf2f(xt[(size_t)c4.z*Hh + lane]);
    acc += w3*bf2f(xt[(size_t)c4.w*Hh + lane]);
  }
  for (; i < end; ++i){ int c = cp[i]; acc += (cdm*dv[c])*bf2f(xt[(size_t)c*Hh + lane]); }
  float o = s1*acc;
  if (s2 != 0.f) o += s2*bf2f(xb0[(size_t)gw*Hh + lane]);
  outp[(size_t)gw*Hh + lane] = f2bf(o);
}

// ---------------------------------------------------------------- fold cheb_W into conv_W
__global__ void k_ww(const float* __restrict__ chebW, const float* __restrict__ chebb,
    const float* __restrict__ convW, const float* __restrict__ convb, float* __restrict__ WW, float* __restrict__ c0)
{
  int idx = blockIdx.x*256 + threadIdx.x;
  if (idx < 3*Tt*Hh*Oo){
    int oc = idx % Oo; int j = (idx/Oo) % Hh; int t = (idx/(Oo*Hh)) % Tt; int i = idx/(Oo*Hh*Tt);
    const float* cw = chebW + ((size_t)i*Hh + j)*HC + (HC-KW);
    const float* vw = convW + ((size_t)oc*Tt + t)*KW;
    float s = 0.f;
    for (int k = 0; k < KW; ++k) s += cw[k]*vw[k];
    WW[idx] = s;
  }
  if (blockIdx.x == 0 && threadIdx.x < Oo){
    int oc = threadIdx.x;
    float s = convb[oc];
    for (int t = 0; t < Tt; ++t){
      const float* vw = convW + ((size_t)oc*Tt + t)*KW;
      for (int k = 0; k < KW; ++k) s += chebb[(HC-KW)+k]*vw[k];
    }
    c0[oc] = s;
  }
}

// ---------------------------------------------------------------- fused cheb-GEMM + temporal conv + sigmoid
__global__ __launch_bounds__(256) void k_final(const __hip_bfloat16* __restrict__ tx0,
    const __hip_bfloat16* __restrict__ tx1, const __hip_bfloat16* __restrict__ tx2,
    const float* __restrict__ WW, const float* __restrict__ c0, float* __restrict__ outp)
{
  __shared__ float xs[64][65];
  __shared__ float ww[64][12];
  const int tid = threadIdx.x;
  const int n0 = blockIdx.x*64;
  const int n = tid & 63, ob = (tid >> 6)*3;
  float acc[3] = {0.f, 0.f, 0.f};
  for (int it = 0; it < 3*Tt; ++it){
    int ii = it / Tt, t = it % Tt;
    const __hip_bfloat16* tx = (ii == 0) ? tx0 : (ii == 1) ? tx1 : tx2;
    __syncthreads();
    for (int idx = tid; idx < 64*64; idx += 256){
      int mm = idx >> 6, j = idx & 63;
      int m = n0 + mm;
      xs[mm][j] = (m < Mn) ? bf2f(tx[((size_t)t*Mn + m)*Hh + j]) : 0.f;
    }
    for (int idx = tid; idx < 64*Oo; idx += 256)
      ((float*)ww)[idx] = WW[((size_t)(ii*Tt + t)*Hh)*Oo + idx];
    __syncthreads();
    #pragma unroll 8
    for (int j = 0; j < 64; ++j){
      float x = xs[n][j];
      acc[0] += x*ww[j][ob+0];
      acc[1] += x*ww[j][ob+1];
      acc[2] += x*ww[j][ob+2];
    }
  }
  int m = n0 + n;
  if (m < Mn){
    #pragma unroll
    for (int q = 0; q < 3; ++q) outp[(size_t)m*Oo + ob + q] = sigm(acc[q] + c0[ob+q]);
  }
}

// ================================================================ host
extern "C" void kernel_launch(void* const* d_in, const int* in_sizes, int n_in,
                              void* d_out, int out_size, void* d_ws, size_t ws_size,
                              hipStream_t stream)
{
  const float* nf    = (const float*)d_in[0];
  const int*   ei    = (const int*)d_in[1];
  const float* Wih0  = (const float*)d_in[2];
  const float* Whh0  = (const float*)d_in[3];
  const float* bih0  = (const float*)d_in[4];
  const float* bhh0  = (const float*)d_in[5];
  const float* Wih1  = (const float*)d_in[6];
  const float* Whh1  = (const float*)d_in[7];
  const float* bih1  = (const float*)d_in[8];
  const float* bhh1  = (const float*)d_in[9];
  const float* lns   = (const float*)d_in[10];
  const float* lnb   = (const float*)d_in[11];
  const float* chebW = (const float*)d_in[12];
  const float* chebb = (const float*)d_in[13];
  const float* convW = (const float*)d_in[14];
  const float* convb = (const float*)d_in[15];
  float* outp = (float*)d_out;

  char* base = (char*)d_ws;
  size_t off = 0;
  auto alloc = [&](size_t bytes)->char*{ char* p = base + off; off += (bytes + 255) & ~(size_t)255; return p; };

  __hip_bfloat16* y0  = (__hip_bfloat16*)alloc((size_t)Tt*Mn*C2*2);
  __hip_bfloat16* tx1 = y0;
  __hip_bfloat16* tx2 = y0 + (size_t)Tt*Mn*Hh;
  __hip_bfloat16* gi  = (__hip_bfloat16*)alloc((size_t)Tt*Mn*Gg*2);
  unsigned* pair = (unsigned*)gi;          // overlaps gi: pair dead before k_gi1m writes gi
  __hip_bfloat16* xbt = (__hip_bfloat16*)alloc((size_t)Tt*Mn*Hh*2);
  unsigned short* col16 = (unsigned short*)alloc((size_t)Tt*Ee*2);
  int*   deg  = (int*)alloc((size_t)Tt*Mn*4);
  int*   rp   = (int*)alloc((size_t)Tt*(Mn+1)*4);
  int*   bcnt = (int*)alloc((size_t)Tt*NB*4);
  int*   bfill= (int*)alloc((size_t)Tt*NB*4);
  int*   rpb  = (int*)alloc((size_t)Tt*(NB+1)*4);
  float* uA   = (float*)alloc((size_t)Tt*Mn*4);
  float* uB   = (float*)alloc((size_t)Tt*Mn*4);
  float* dinv = (float*)alloc((size_t)Tt*Mn*4);
  float* nrm2 = (float*)alloc((size_t)76*Tt*4);
  float* dotb = (float*)alloc((size_t)Tt*4);
  float* lamc = (float*)alloc((size_t)2*Tt*4);
  float* WW   = (float*)alloc((size_t)3*Tt*Hh*Oo*4);
  float* c0   = (float*)alloc((size_t)Oo*4);
  __hip_bfloat16* Wbf = (__hip_bfloat16*)alloc((size_t)Gg*C2*2);
  (void)ws_size; (void)in_sizes; (void)n_in; (void)out_size;

  // CSR build: bucket histogram -> bucket scan -> partition -> per-bucket counting sort (emits rp+deg)
  k_init<<<(Tt*Mn + 255)/256, 256, 0, stream>>>(nrm2, dotb, uA, bcnt, bfill);
  k_bcnt<<<Tt*BPT, 256, 0, stream>>>(ei, bcnt);
  k_bscan<<<Tt, 256, 0, stream>>>(bcnt, rpb);
  k_part2<<<Tt*BPT, 256, 0, stream>>>(ei, rpb, bfill, pair);
  k_csr2<<<Tt*NB, 256, 0, stream>>>(rpb, pair, col16, rp, deg);
  k_dinv<<<(Tt*Mn + 255)/256, 256, 0, stream>>>(deg, dinv);

  // GRU stack (layer-1 forward direction is dead code -> skipped)
  k_wcvt<<<(Gg*C2 + 255)/256, 256, 0, stream>>>(Wih1 + (size_t)Gg*C2, Wbf);
  k_gru0<<<(Mn + 31)/32, 256, 0, stream>>>(nf, Wih0, Whh0, bih0, bhh0, y0);
  {
    int waves = Tt*((Mn + 31)/32);
    k_gi1m<<<(waves + 3)/4, 256, 0, stream>>>(y0, Wbf, bih1 + Gg, gi);
  }
  k_gru1r<<<(Mn + 31)/32, 256, 0, stream>>>(gi, Whh1 + (size_t)Gg*Hh, bhh1 + Gg, lns, lnb, xbt);

  // power iteration: 75 rounds + 1 Rayleigh round; full u_t in LDS per block, 21 blocks/t
  for (int r = 1; r <= 76; ++r){
    const float* uin = ((r-1) & 1) ? uB : uA;
    float* uout = (r & 1) ? uB : uA;
    int fin = (r == 76) ? 1 : 0;
    k_pit3<<<Tt*CHK, 1024, 0, stream>>>(rp, col16, uin, uout,
                                        nrm2 + (size_t)(r-1)*Tt, nrm2 + (size_t)(fin ? 75 : r)*Tt, dotb, fin);
  }
  k_lamfin<<<1, 64, 0, stream>>>(nrm2, dotb, lamc);

  // Chebyshev: tx1 = Lhat(x), tx2 = 2*Lhat(tx1) - x
  k_cheb<<<(Tt*Mn)/4, 256, 0, stream>>>(xbt, xbt, tx1, rp, col16, dinv, lamc, 1.f, 0.f);
  k_cheb<<<(Tt*Mn)/4, 256, 0, stream>>>(tx1, xbt, tx2, rp, col16, dinv, lamc, 2.f, -1.f);

  // folded cheb-GEMM + conv + sigmoid
  k_ww<<<(3*Tt*Hh*Oo + 255)/256, 256, 0, stream>>>(chebW, chebb, convW, convb, WW, c0);
  k_final<<<(Mn + 63)/64, 256, 0, stream>>>(xbt, tx1, tx2, WW, c0, outp);
}